// Round 18
// baseline (145.604 us; speedup 1.0000x reference)
//
#include <hip/hip_runtime.h>
#include <cstdint>
#include <cstddef>

#define BB 128
#define VV 128000
#define TT 4096
#define NWIN 2048            // windows = 128 rows x 16 slices
#define WVR (VV / 16)        // 8000 tokens per window
#define WHW (WVR / 4)        // 2000 packed words
#define NT 256
#define EXC_CAP 96

typedef float vf4 __attribute__((ext_vector_type(4)));

// Round-28 = round-27 resubmitted verbatim (GPU acquisition timeout — the
// granularity-8 interleave is unmeasured; holding the kernel fixed).
// Round-27 = round-23 with ONE change: role assigned by (L>>3)&1 (groups of
// 8), id = (L>>4)*8 + (L&7).
// r16-measured r23: enforce_fused 43.0 us, occ 68%, hbm 2.4 TB/s — EXACTLY
// additive stream(~22)+hist(~21). Mechanism found: 2048 stream blocks =
// 8/CU x 256 CU = full residency; range assignment fills the whole machine
// with stream blocks first, hist blocks only enter as they retire ->
// guaranteed phase serialization, zero co-residency. r12's parity variant
// had the opposite failure (spatial split: stream on 4 XCDs = 2x stream
// time). Granularity-8 interleave gives BOTH: each role stripes all 8 XCDs
// (L&7 preserved within each group) AND dispatch alternates roles every 8
// blocks -> each CU holds ~4 stream + ~4 hist blocks concurrently; hist
// VALU/LDS work hides under stream memory traffic.
// Exception machinery unchanged from r21/r23 (passed correctness twice).
// SENT = 0xFF7F0000 (finite bf16 0xFF7F) — r1/r2 lessons. RINV <=1 ulp.

__device__ __forceinline__ void win_decode(int id, int& b, int& vbase) {
  // XCD-aware swizzle: 16 windows of a row land on one XCD (gen L2 locality)
  const int xcd = id & 7, q = id >> 3, s = q & 15;
  b = (q >> 4) * 8 + xcd;
  vbase = s * WVR;
}

__device__ __forceinline__ int block_detect(const unsigned char* maskb,
                                            unsigned* det, int tid) {
  if (tid == 0) *det = 0u;
  __syncthreads();
  const uint4* md = (const uint4*)maskb;
  unsigned a = 0u, c = 0u;
#pragma unroll
  for (int k = 0; k < 4; ++k) {          // 256 threads x 4 uint4 = 16 KB scan
    uint4 w = md[tid + k * NT];
    unsigned o = w.x | w.y | w.z | w.w;
    a |= o & 0x000000FFu;
    c |= o & 0xFFFFFF00u;
  }
  unsigned long long ba = __ballot(a != 0u);
  unsigned long long bc = __ballot(c != 0u);
  if ((tid & 63) == 0) {
    unsigned bits = (ba ? 1u : 0u) | (bc ? 2u : 0u);
    if (bits) atomicOr(det, bits);
  }
  __syncthreads();
  return (*det == 3u) ? 1 : 3;   // u8 vs 32-bit word mode
}

template<int ML>
__global__ __launch_bounds__(NT) void enforce_fused(
    const float* __restrict__ logits,
    const int*  __restrict__ gen,
    const unsigned char* __restrict__ maskb,
    const int*  __restrict__ req,
    float* __restrict__ out,
    unsigned* __restrict__ wsc,       // [NWIN] exception counts
    uint2*    __restrict__ wse,       // [NWIN][EXC_CAP] {idx-in-window, bits(val)}
    int R)
{
  __shared__ unsigned hist[WHW];   // 8 KB (hist role only)
  __shared__ uint2 exc[EXC_CAP];
  __shared__ unsigned nexc;
  const int tid = threadIdx.x;
  const int L   = blockIdx.x;      // 4096
  // role interleave at granularity 8: both roles stripe all XCDs AND
  // alternate in dispatch order -> per-CU co-residency of roles.
  const bool is_stream = (((L >> 3) & 1) == 0);
  const int id  = ((L >> 4) << 3) | (L & 7);   // [0, NWIN) bijective per role
  int b, vbase; win_decode(id, b, vbase);

  int ml = ML;
  if constexpr (ML == -1) {
    __shared__ unsigned det;
    ml = block_detect(maskb, &det, tid);
  }

  const float SENT = __uint_as_float(0xFF7F0000u);
  const float RINV = 1.0f / 1.2f;
  auto forb1 = [&](int t) -> bool {
    if (ml == 1) return maskb[t] != 0;
    return ((const int*)maskb)[t] != 0;   // i32 1 / f32 1.0f both nonzero
  };

  if (is_stream) {
    // ================= STREAM ROLE: pure masked copy, x4 unroll =============
    const vf4* lrow = (const vf4*)(logits + (size_t)b * VV + vbase);
    vf4*       orow = (vf4*)(out + (size_t)b * VV + vbase);
    const unsigned* m8  = (const unsigned*)(maskb + vbase);
    const int4*     m32 = (const int4*)((const int*)maskb + vbase);
    auto lmask = [&](int i) -> unsigned {
      if (ml == 1) return m8[i];
      int4 m = m32[i];
      return (m.x ? 1u : 0u) | (m.y ? 0x100u : 0u) |
             (m.z ? 0x10000u : 0u) | (m.w ? 0x1000000u : 0u);
    };
    for (int i0 = tid; i0 < WHW; i0 += 4 * NT) {   // 2 outer iterations
      const int i1 = i0 + NT, i2 = i0 + 2 * NT, i3 = i0 + 3 * NT;
      const bool p1 = i1 < WHW, p2 = i2 < WHW, p3 = i3 < WHW;
      vf4 x0 = lrow[i0];           unsigned f0 = lmask(i0);
      vf4 x1 = {0,0,0,0}, x2 = {0,0,0,0}, x3 = {0,0,0,0};
      unsigned f1 = 0, f2 = 0, f3 = 0;
      if (p1) { x1 = lrow[i1]; f1 = lmask(i1); }
      if (p2) { x2 = lrow[i2]; f2 = lmask(i2); }
      if (p3) { x3 = lrow[i3]; f3 = lmask(i3); }
      vf4 r0, r1, r2, r3;
#pragma unroll
      for (int j = 0; j < 4; ++j) r0[j] = ((f0 >> (j*8)) & 0xFFu) ? SENT : x0[j];
      orow[i0] = r0;
      if (p1) {
#pragma unroll
        for (int j = 0; j < 4; ++j) r1[j] = ((f1 >> (j*8)) & 0xFFu) ? SENT : x1[j];
        orow[i1] = r1;
      }
      if (p2) {
#pragma unroll
        for (int j = 0; j < 4; ++j) r2[j] = ((f2 >> (j*8)) & 0xFFu) ? SENT : x2[j];
        orow[i2] = r2;
      }
      if (p3) {
#pragma unroll
        for (int j = 0; j < 4; ++j) r3[j] = ((f3 >> (j*8)) & 0xFFu) ? SENT : x3[j];
        orow[i3] = r3;
      }
    }
  } else {
    // ================= HIST ROLE: exceptions -> ws ==========================
    for (int i = tid; i < WHW; i += NT) hist[i] = 0u;
    if (tid == 0) nexc = 0u;
    __syncthreads();

    // gen scan; atomicAdd return catches the unique 2->3 transition.
    // Penalty value is a pure function of logits -> computable NOW.
    const int4* grow = (const int4*)(gen + b * TT);
    for (int i = tid; i < TT / 4; i += NT) {       // 4 iterations
      int4 g = grow[i];
      const int t4[4] = {g.x, g.y, g.z, g.w};
#pragma unroll
      for (int j = 0; j < 4; ++j) {
        const int t = t4[j];
        unsigned d = (unsigned)(t - vbase);
        if (d < (unsigned)WVR) {
          const unsigned sh = (d & 3u) * 8u;
          unsigned old = atomicAdd(&hist[d >> 2], 1u << sh);
          if (((old >> sh) & 0xFFu) == 2u && !forb1(t)) {
            float v  = logits[(size_t)b * VV + t];
            float pv = (v > 0.0f) ? v * RINV : v * 1.2f;
            unsigned k = atomicAdd(&nexc, 1u);
            if (k < EXC_CAP) exc[k] = make_uint2(d, __float_as_uint(pv));
          }
        }
      }
    }
    __syncthreads();   // cnt final before boost check

    // boosts: req tokens in-window, cnt==0, allowed. Dedup to first
    // occurrence; value = logits + 5*multiplicity (matches reference
    // duplicate scatter-add).
    for (int r = tid; r < R; r += NT) {
      const int t = req[r];
      unsigned d = (unsigned)(t - vbase);
      if (d < (unsigned)WVR) {
        bool first = true; int mult = 0;
        for (int j = 0; j < R; ++j) {
          if (req[j] == t) { if (j < r) first = false; ++mult; }
        }
        if (first) {
          unsigned cnt = (hist[d >> 2] >> ((d & 3u) * 8u)) & 0xFFu;
          if (cnt == 0u && !forb1(t)) {
            float v = logits[(size_t)b * VV + t] + 5.0f * (float)mult;
            unsigned k = atomicAdd(&nexc, 1u);
            if (k < EXC_CAP) exc[k] = make_uint2(d, __float_as_uint(v));
          }
        }
      }
    }
    __syncthreads();

    unsigned n = nexc < EXC_CAP ? nexc : EXC_CAP;
    if (tid == 0) wsc[id] = n;
    for (unsigned k = tid; k < n; k += NT)
      wse[(size_t)id * EXC_CAP + k] = exc[k];
  }
}

__global__ __launch_bounds__(NT) void apply_exc(
    float* __restrict__ out,
    const unsigned* __restrict__ wsc,
    const uint2* __restrict__ wse)
{
  const int w = blockIdx.x * NT + threadIdx.x;
  if (w >= NWIN) return;
  int b, vbase; win_decode(w, b, vbase);
  unsigned n = wsc[w]; if (n > EXC_CAP) n = EXC_CAP;
  const uint2* e = wse + (size_t)w * EXC_CAP;
  for (unsigned k = 0; k < n; ++k) {
    uint2 q = e[k];
    out[(size_t)b * VV + vbase + q.x] = __uint_as_float(q.y);
  }
}

// ---------------- fallback monolith (r16, measured 123.9 total) -------------
template<int ML>
__global__ __launch_bounds__(NT) void enforce_mono(
    const float* __restrict__ logits,
    const int*  __restrict__ gen,
    const unsigned char* __restrict__ maskb,
    const int*  __restrict__ req,
    float* __restrict__ out,
    int R)
{
  __shared__ unsigned hist[WHW];
  __shared__ int cand[64];
  __shared__ unsigned ncand;
  const int tid = threadIdx.x;
  int b, vbase; win_decode(blockIdx.x, b, vbase);

  int ml = ML;
  if constexpr (ML == -1) {
    __shared__ unsigned det;
    ml = block_detect(maskb, &det, tid);
  }
  for (int i = tid; i < WHW; i += NT) hist[i] = 0u;
  if (tid == 0) ncand = 0u;
  __syncthreads();

  const float SENT = __uint_as_float(0xFF7F0000u);
  const float RINV = 1.0f / 1.2f;
  auto forb1 = [&](int t) -> bool {
    if (ml == 1) return maskb[t] != 0;
    return ((const int*)maskb)[t] != 0;
  };
  const vf4* lrow = (const vf4*)(logits + (size_t)b * VV + vbase);
  vf4*       orow = (vf4*)(out + (size_t)b * VV + vbase);
  const unsigned* m8  = (const unsigned*)(maskb + vbase);
  const int4*     m32 = (const int4*)((const int*)maskb + vbase);
  auto lmask = [&](int i) -> unsigned {
    if (ml == 1) return m8[i];
    int4 m = m32[i];
    return (m.x ? 1u : 0u) | (m.y ? 0x100u : 0u) |
           (m.z ? 0x10000u : 0u) | (m.w ? 0x1000000u : 0u);
  };
  for (int i0 = tid; i0 < WHW; i0 += 2 * NT) {
    const int i1 = i0 + NT;
    const bool p1 = (i1 < WHW);
    vf4 x0 = lrow[i0]; unsigned f0 = lmask(i0);
    vf4 x1 = {0,0,0,0}; unsigned f1 = 0u;
    if (p1) { x1 = lrow[i1]; f1 = lmask(i1); }
    vf4 r0, r1;
#pragma unroll
    for (int j = 0; j < 4; ++j) r0[j] = ((f0 >> (j*8)) & 0xFFu) ? SENT : x0[j];
    orow[i0] = r0;
    if (p1) {
#pragma unroll
      for (int j = 0; j < 4; ++j) r1[j] = ((f1 >> (j*8)) & 0xFFu) ? SENT : x1[j];
      orow[i1] = r1;
    }
  }
  const int4* grow = (const int4*)(gen + b * TT);
  for (int i = tid; i < TT / 4; i += NT) {
    int4 g = grow[i];
    const int t4[4] = {g.x, g.y, g.z, g.w};
#pragma unroll
    for (int j = 0; j < 4; ++j) {
      const int t = t4[j];
      unsigned d = (unsigned)(t - vbase);
      if (d < (unsigned)WVR) {
        const unsigned sh = (d & 3u) * 8u;
        unsigned old = atomicAdd(&hist[d >> 2], 1u << sh);
        if (((old >> sh) & 0xFFu) == 2u) {
          unsigned k = atomicAdd(&ncand, 1u);
          if (k < 64u) cand[k] = t;
        }
      }
    }
  }
  __syncthreads();
  const unsigned nc = ncand < 64u ? ncand : 64u;
  for (unsigned k = tid; k < nc; k += NT) {
    const int t = cand[k];
    if (!forb1(t)) {
      float v = logits[(size_t)b * VV + t];
      out[(size_t)b * VV + t] = (v > 0.0f) ? v * RINV : v * 1.2f;
    }
  }
  for (int r = tid; r < R; r += NT) {
    const int t = req[r];
    unsigned d = (unsigned)(t - vbase);
    if (d < (unsigned)WVR) {
      unsigned cnt = (hist[d >> 2] >> ((d & 3u) * 8u)) & 0xFFu;
      if (cnt == 0u && !forb1(t))
        atomicAdd(out + (size_t)b * VV + t, 5.0f);
    }
  }
}

extern "C" void kernel_launch(void* const* d_in, const int* in_sizes, int n_in,
                              void* d_out, int out_size, void* d_ws, size_t ws_size,
                              hipStream_t stream) {
  const float* logits = (const float*)d_in[0];
  const int*   gen    = (const int*)d_in[1];
  const unsigned char* maskb = (const unsigned char*)d_in[2];
  const int*   req    = (const int*)d_in[3];
  float* out = (float*)d_out;

  int R = in_sizes[3];
  if (R >= 256 && (R & 3) == 0) R >>= 2;   // bytes -> elements

  int ml;
  if (in_sizes[0] == BB * VV * 4) {        // bytes mode
    ml = (in_sizes[2] == VV) ? 1 : 3;      // 128000 -> u8 ; 512000 -> 32-bit
  } else {
    ml = -1;
  }

  const size_t NEED = 8192 + (size_t)NWIN * EXC_CAP * sizeof(uint2);
  if (d_ws != nullptr && ws_size >= NEED) {
    unsigned* wsc = (unsigned*)d_ws;
    uint2*    wse = (uint2*)((char*)d_ws + 8192);
    if (ml == 1)
      enforce_fused<1><<<2 * NWIN, NT, 0, stream>>>(logits, gen, maskb, req, out, wsc, wse, R);
    else if (ml == 3)
      enforce_fused<3><<<2 * NWIN, NT, 0, stream>>>(logits, gen, maskb, req, out, wsc, wse, R);
    else
      enforce_fused<-1><<<2 * NWIN, NT, 0, stream>>>(logits, gen, maskb, req, out, wsc, wse, R);
    apply_exc<<<(NWIN + NT - 1) / NT, NT, 0, stream>>>(out, wsc, wse);
  } else {
    if (ml == 1)      enforce_mono<1><<<NWIN, NT, 0, stream>>>(logits, gen, maskb, req, out, R);
    else if (ml == 3) enforce_mono<3><<<NWIN, NT, 0, stream>>>(logits, gen, maskb, req, out, R);
    else              enforce_mono<-1><<<NWIN, NT, 0, stream>>>(logits, gen, maskb, req, out, R);
  }
}